// Round 1
// baseline (329.948 us; speedup 1.0000x reference)
//
#include <hip/hip_runtime.h>
#include <math.h>

#define TOK_PER_BLK 4
#define THREADS 256
#define NROWS 24
#define PCOL 17        // 16 partials + 1 pad (odd stride -> conflict-free)
#define TAU_INV 20.0f  // 1/0.05

// One block = 4 tokens, 256 threads. Thread tid holds float4 (q*256+tid) of each
// token in REGISTERS (q = stream). Weights are NOT loaded to registers anymore:
// R4 showed VGPR_Count=84 vs a ~144-reg live set -> ~70MiB of scratch spill
// (WRITE_SIZE 198MiB vs 128MiB output). Weight rows now stream global->LDS via
// async global_load_lds (width 16), double-buffered with counted vmcnt(4) +
// raw s_barrier (a __syncthreads here would drain vmcnt(0) and serialize the
// prefetch). Live set ~100 VGPRs -> no spill; LDS 40.3KB -> 4 blocks/CU.
__device__ __forceinline__ void async_cp16(const float* gsrc, float* ldst) {
    __builtin_amdgcn_global_load_lds(
        (const __attribute__((address_space(1))) void*)gsrc,
        (__attribute__((address_space(3))) void*)ldst, 16, 0, 0);
}

__global__ __launch_bounds__(THREADS, 4)
void hc_fused(const float* __restrict__ resid,
              const float* __restrict__ gamma,
              const float* __restrict__ w_res,
              const float* __restrict__ w_pre,
              const float* __restrict__ w_post,
              const float* __restrict__ beta_res,
              const float* __restrict__ beta_pre,
              const float* __restrict__ beta_post,
              const float* __restrict__ p_alpha_res,
              const float* __restrict__ p_alpha_pre,
              const float* __restrict__ p_alpha_post,
              float* __restrict__ out)
{
    __shared__ float sh_w[2][4096];                       // 32 KB weight-row dbuf
    __shared__ float sh_part[NROWS * TOK_PER_BLK][PCOL];  // 6.5 KB dot partials
    __shared__ float sh_ssqp[TOK_PER_BLK][PCOL];          // sumsq partials
    __shared__ float sh_raw[TOK_PER_BLK][NROWS];
    __shared__ float sh_ssq[TOK_PER_BLK];
    __shared__ float sh_H[TOK_PER_BLK][NROWS];  // [0..15]=H_res, [16..19]=H_pre, [20..23]=H_post

    const int tid  = threadIdx.x;
    const int wave = tid >> 6;
    const int lane = tid & 63;
    const long tok0 = (long)blockIdx.x * TOK_PER_BLK;

    // ---------------- Phase 1: global -> registers + sumsq ----------------
    const float4* hp = (const float4*)resid + tok0 * 1024;
    float4 p[TOK_PER_BLK][4];
    #pragma unroll
    for (int m = 0; m < TOK_PER_BLK; ++m) {
        #pragma unroll
        for (int q = 0; q < 4; ++q)
            p[m][q] = hp[m * 1024 + q * 256 + tid];
    }
    #pragma unroll
    for (int m = 0; m < TOK_PER_BLK; ++m) {
        float s = 0.f;
        #pragma unroll
        for (int q = 0; q < 4; ++q) {
            float4 v = p[m][q];
            s += v.x * v.x + v.y * v.y + v.z * v.z + v.w * v.w;
        }
        s += __shfl_xor(s, 4, 64);
        s += __shfl_xor(s, 8, 64);
        s += __shfl_xor(s, 16, 64);
        s += __shfl_xor(s, 32, 64);
        if (lane < 4) sh_ssqp[m][(wave << 2) | lane] = s;
    }

    // gamma+1 in registers
    float4 g[4];
    {
        const float4* gp = (const float4*)gamma;
        #pragma unroll
        for (int q = 0; q < 4; ++q) {
            float4 gv = gp[q * 256 + tid];
            g[q] = make_float4(gv.x + 1.f, gv.y + 1.f, gv.z + 1.f, gv.w + 1.f);
        }
    }

    // ---------------- Phase 2: 24 dot products, LDS-staged weights ----------
    // dot(w, x*(g+1)) = dot(w*(g+1), x): fold gamma into weights at use.
    auto row_ptr = [&](int e) -> const float* {
        return (e < 16) ? (w_res + (size_t)e * 4096)
             : (e < 20) ? (w_pre + (size_t)(e - 16) * 4096)
                        : (w_post + (size_t)(e - 20) * 4096);
    };
    // Wave w issues 4 DMAs of 1KB each; LDS row is a linear copy of the global
    // row (global_load_lds dest = wave-uniform base + lane*16, so LDS layout
    // must be linear in lane order).
    auto issue_row = [&](int e, int b) {
        const float* src = row_ptr(e);
        #pragma unroll
        for (int j = 0; j < 4; ++j) {
            const int seg = ((wave << 2) | j) << 8;    // float index of 256-float segment
            async_cp16(src + seg + (lane << 2), &sh_w[b][seg]);
        }
    };

    issue_row(0, 0);
    #pragma unroll 1
    for (int r = 0; r < NROWS; ++r) {
        const int b = r & 1;
        if (r + 1 < NROWS) {
            issue_row(r + 1, b ^ 1);
            // 8 outstanding (row r + row r+1); wait until only r+1's 4 remain.
            asm volatile("s_waitcnt vmcnt(4)" ::: "memory");
        } else {
            asm volatile("s_waitcnt vmcnt(0)" ::: "memory");
        }
        __builtin_amdgcn_s_barrier();            // (1) buf[b] fully written, all waves
        __builtin_amdgcn_sched_barrier(0);       // pin ds_reads after the barrier

        const float4* wr = (const float4*)sh_w[b];
        float4 w0 = wr[tid], w1 = wr[256 + tid], w2 = wr[512 + tid], w3 = wr[768 + tid];
        w0 = make_float4(w0.x * g[0].x, w0.y * g[0].y, w0.z * g[0].z, w0.w * g[0].w);
        w1 = make_float4(w1.x * g[1].x, w1.y * g[1].y, w1.z * g[1].z, w1.w * g[1].w);
        w2 = make_float4(w2.x * g[2].x, w2.y * g[2].y, w2.z * g[2].z, w2.w * g[2].w);
        w3 = make_float4(w3.x * g[3].x, w3.y * g[3].y, w3.z * g[3].z, w3.w * g[3].w);
        #pragma unroll
        for (int m = 0; m < TOK_PER_BLK; ++m) {
            float a = w0.x * p[m][0].x + w0.y * p[m][0].y + w0.z * p[m][0].z + w0.w * p[m][0].w
                    + w1.x * p[m][1].x + w1.y * p[m][1].y + w1.z * p[m][1].z + w1.w * p[m][1].w
                    + w2.x * p[m][2].x + w2.y * p[m][2].y + w2.z * p[m][2].z + w2.w * p[m][2].w
                    + w3.x * p[m][3].x + w3.y * p[m][3].y + w3.z * p[m][3].z + w3.w * p[m][3].w;
            a += __shfl_xor(a, 4, 64);
            a += __shfl_xor(a, 8, 64);
            a += __shfl_xor(a, 16, 64);
            a += __shfl_xor(a, 32, 64);
            if (lane < 4) sh_part[r * TOK_PER_BLK + m][(wave << 2) | lane] = a;
        }
        __builtin_amdgcn_s_barrier();            // (2) all waves done READING buf[b];
                                                 // next iter may DMA into buf[b]
    }
    __syncthreads();   // lgkm drain -> sh_part/sh_ssqp visible to reducers

    // ---------------- Reduce: 16 partials per (row,token) ----------------
    if (tid < NROWS * TOK_PER_BLK) {             // 96 threads: one (row,token) each
        const int e = tid >> 2, m = tid & 3;
        const float* src = &sh_part[tid][0];
        float s = 0.f;
        #pragma unroll
        for (int j = 0; j < 16; ++j) s += src[j];
        sh_raw[m][e] = s;
    } else if (tid < NROWS * TOK_PER_BLK + TOK_PER_BLK) {
        const int m = tid - NROWS * TOK_PER_BLK;
        float s = 0.f;
        #pragma unroll
        for (int j = 0; j < 16; ++j) s += sh_ssqp[m][j];
        sh_ssq[m] = s;
    }
    __syncthreads();

    // ---------------- Phase 3: sinkhorn + gates (one wave per token) --------
    {
        const int m   = wave;
        const int idx = lane & 15;     // (i,j): i = idx>>2, j = idx&3
        const int jj  = idx & 3;

        float ss    = sh_ssq[m];
        float scale = 64.0f / fmaxf(sqrtf(ss), 1e-12f);

        const float a_res  = p_alpha_res[0];
        const float a_pre  = p_alpha_pre[0];
        const float a_post = p_alpha_post[0];

        float Z = (beta_res[idx] + a_res * scale * sh_raw[m][idx]) * TAU_INV;
        float u = 0.f, v = 0.f;
        #pragma unroll 1
        for (int it = 0; it < 10; ++it) {
            float t  = Z + v;
            float mx = t;
            mx = fmaxf(mx, __shfl_xor(mx, 1, 64));
            mx = fmaxf(mx, __shfl_xor(mx, 2, 64));
            float sm = __expf(t - mx);
            sm += __shfl_xor(sm, 1, 64);
            sm += __shfl_xor(sm, 2, 64);
            u = -(mx + __logf(sm));
            t  = Z + u;
            mx = t;
            mx = fmaxf(mx, __shfl_xor(mx, 4, 64));
            mx = fmaxf(mx, __shfl_xor(mx, 8, 64));
            sm = __expf(t - mx);
            sm += __shfl_xor(sm, 4, 64);
            sm += __shfl_xor(sm, 8, 64);
            v = -(mx + __logf(sm));
        }
        float P = __expf(Z + u + v);
        if (lane < 16) sh_H[m][idx] = P;

        float lpre = beta_pre[jj] + a_pre * scale * sh_raw[m][16 + jj];
        float mxp = lpre;
        mxp = fmaxf(mxp, __shfl_xor(mxp, 1, 64));
        mxp = fmaxf(mxp, __shfl_xor(mxp, 2, 64));
        float ep = __expf(lpre - mxp);
        float sp = ep;
        sp += __shfl_xor(sp, 1, 64);
        sp += __shfl_xor(sp, 2, 64);
        float hpre = ep / sp;
        float lpost = beta_post[jj] + a_post * scale * sh_raw[m][20 + jj];
        float hpost = 2.0f / (1.0f + __expf(-lpost));
        if (lane < 4) { sh_H[m][16 + jj] = hpre; sh_H[m][20 + jj] = hpost; }
    }
    __syncthreads();

    // ---------------- Phase 4: remix + branch, store (FULLY UNROLLED) -------
    #pragma unroll
    for (int m = 0; m < TOK_PER_BLK; ++m) {
        float Hr[16], Hp[4], Ho[4];
        #pragma unroll
        for (int k = 0; k < 16; ++k) Hr[k] = sh_H[m][k];
        #pragma unroll
        for (int s = 0; s < 4; ++s) { Hp[s] = sh_H[m][16 + s]; Ho[s] = sh_H[m][20 + s]; }

        float4 br;
        br.x = Hp[0]*p[m][0].x + Hp[1]*p[m][1].x + Hp[2]*p[m][2].x + Hp[3]*p[m][3].x;
        br.y = Hp[0]*p[m][0].y + Hp[1]*p[m][1].y + Hp[2]*p[m][2].y + Hp[3]*p[m][3].y;
        br.z = Hp[0]*p[m][0].z + Hp[1]*p[m][1].z + Hp[2]*p[m][2].z + Hp[3]*p[m][3].z;
        br.w = Hp[0]*p[m][0].w + Hp[1]*p[m][1].w + Hp[2]*p[m][2].w + Hp[3]*p[m][3].w;

        float4* op = (float4*)out + (tok0 + m) * 1024;
        #pragma unroll
        for (int i = 0; i < 4; ++i) {
            float4 o;
            o.x = Hr[i*4+0]*p[m][0].x + Hr[i*4+1]*p[m][1].x + Hr[i*4+2]*p[m][2].x + Hr[i*4+3]*p[m][3].x + Ho[i]*br.x;
            o.y = Hr[i*4+0]*p[m][0].y + Hr[i*4+1]*p[m][1].y + Hr[i*4+2]*p[m][2].y + Hr[i*4+3]*p[m][3].y + Ho[i]*br.y;
            o.z = Hr[i*4+0]*p[m][0].z + Hr[i*4+1]*p[m][1].z + Hr[i*4+2]*p[m][2].z + Hr[i*4+3]*p[m][3].z + Ho[i]*br.z;
            o.w = Hr[i*4+0]*p[m][0].w + Hr[i*4+1]*p[m][1].w + Hr[i*4+2]*p[m][2].w + Hr[i*4+3]*p[m][3].w + Ho[i]*br.w;
            op[i * 256 + tid] = o;
        }
    }
}

extern "C" void kernel_launch(void* const* d_in, const int* in_sizes, int n_in,
                              void* d_out, int out_size, void* d_ws, size_t ws_size,
                              hipStream_t stream) {
    const float* resid      = (const float*)d_in[0];
    const float* gamma      = (const float*)d_in[1];
    const float* w_res      = (const float*)d_in[2];
    const float* w_pre      = (const float*)d_in[3];
    const float* w_post     = (const float*)d_in[4];
    const float* beta_res   = (const float*)d_in[5];
    const float* beta_pre   = (const float*)d_in[6];
    const float* beta_post  = (const float*)d_in[7];
    const float* alpha_res  = (const float*)d_in[8];
    const float* alpha_pre  = (const float*)d_in[9];
    const float* alpha_post = (const float*)d_in[10];
    float* out = (float*)d_out;

    const int ntok = in_sizes[0] / 4096;          // B*T = 8192
    const int grid = ntok / TOK_PER_BLK;          // 2048

    hc_fused<<<grid, THREADS, 0, stream>>>(resid, gamma, w_res, w_pre, w_post,
                                           beta_res, beta_pre, beta_post,
                                           alpha_res, alpha_pre, alpha_post, out);
}